// Round 4
// baseline (429.240 us; speedup 1.0000x reference)
//
#include <hip/hip_runtime.h>
#include <cmath>

// Problem constants (from reference)
#define N_INPUTS 2048
#define UNITS    2048
#define L_LAYERS 8
#define FANIN    4096
#define TOTAL    18432           // N_INPUTS + L*UNITS

// Decomposition: block = 64 rows x 128 cols of W. 1024 blocks, 4/CU.
#define NTHREADS 256
#define RK       64              // rows (k) per block
#define KC       (FANIN / RK)    // 64 row-chunks
#define JTILE    128             // cols per block
#define JPARTS   (UNITS / JTILE) // 16
#define P_BLOCKS (KC * JPARTS)   // 1024

// ---------------------------------------------------------------------------
// Accumulator design (replaces the 2 MiB partials matrix):
//   each block pre-reduces its 64x128 tile to 128 column sums in LDS and
//   does ONE atomicAdd per column into a 2048-float accumulator (device
//   scope -> visible at the dispatch boundary). The next layer then needs a
//   SINGLE float read (+bias+tanh) to materialize any activation — no
//   col_reduce, no scattered partial traffic in either direction.
// Buffer rotation (3 x 2048 floats): layer i reads buf[(i-1)%3], atomically
// accumulates buf[i%3], and zeroes buf[(i+1)%3] (idle this dispatch: last
// read at layer i-1, next written at layer i+1). buf0 is seeded by an 8 KB
// hipMemsetAsync inside the capture, so every replay re-establishes zeros
// regardless of workspace poison.
// ---------------------------------------------------------------------------
__global__ __launch_bounds__(NTHREADS, 4) void layer_kernel(
    int layer,
    const float* __restrict__ x,
    const int*   __restrict__ node_inds,
    const float* __restrict__ Ws,
    const float* __restrict__ bs,
    float*       __restrict__ outputs,
    const float* __restrict__ accPrev,
    float*       __restrict__ accCur,
    float*       __restrict__ accNext)
{
    const int b  = blockIdx.x;
    const int t  = threadIdx.x;
    const int kc = b >> 4;           // 0..63 : which 64-row chunk
    const int jp = b & 15;           // 0..15 : which 128-col window
    const int jbase = jp * JTILE;
    const int g  = t >> 5;           // row-group 0..7 (8 rows each)
    const int c0 = (t & 31) * 4;     // col offset within tile (float4)

    __shared__ float  gsh[RK];       // gathered activations for 64 rows
    __shared__ float4 red[8][32];    // per-rowgroup partial column sums

    // ---- gather indices first (independent, coalesced, 1 int/thread t<64)
    int idx = 0;
    if (t < RK) idx = node_inds[layer * FANIN + kc * RK + t];

    // ---- W tile: 8 x float4 per thread (16B/lane), issued early so the
    //      stream hides the gather/finalize dependency chains.
    const float* Wp = Ws
        + ((size_t)layer * FANIN + (size_t)kc * RK + (size_t)g * 8) * UNITS
        + jbase + c0;
    float4 w[8];
    #pragma unroll
    for (int r = 0; r < 8; ++r)
        w[r] = *(const float4*)(Wp + (size_t)r * UNITS);

    // ---- gather values: fully thread-parallel (one index per thread).
    //      Current-slot indices cost ONE float read from accPrev (+tanh).
    if (t < RK) {
        float v;
        if (layer == 0) {
            v = (idx < N_INPUTS) ? x[idx] : 0.f;
        } else if (idx < layer * UNITS) {
            v = outputs[idx];
        } else if (idx < (layer + 1) * UNITS) {
            int col = idx - layer * UNITS;
            v = tanhf(accPrev[col] + bs[(layer - 1) * UNITS + col]);
        } else {
            v = 0.f;
        }
        gsh[t] = v;
    }

    // ---- canonical finalize of state slot `layer` (kc==0 blocks own it):
    //      same formula as the gather recompute -> bit-identical values.
    if (kc == 0 && t < JTILE) {
        int col = jbase + t;
        if (layer == 0) {
            outputs[col] = x[col];
        } else {
            float y = tanhf(accPrev[col] + bs[(layer - 1) * UNITS + col]);
            outputs[(size_t)layer * UNITS + col] = y;
        }
    }

    // ---- zero the accumulator for layer+1 (2 floats per block; the buffer
    //      is provably untouched by any other access this dispatch)
    if (t < 2) accNext[b * 2 + t] = 0.f;

    __syncthreads();

    // ---- 8 rows x 4 cols of FMA from prefetched registers
    float4 a; a.x = 0.f; a.y = 0.f; a.z = 0.f; a.w = 0.f;
    #pragma unroll
    for (int r = 0; r < 8; ++r) {
        float gg = gsh[g * 8 + r];
        a.x += gg * w[r].x; a.y += gg * w[r].y;
        a.z += gg * w[r].z; a.w += gg * w[r].w;
    }
    red[g][t & 31] = a;
    __syncthreads();

    // ---- cross-rowgroup reduce + one atomicAdd per owned column
    if (t < 32) {
        float4 s = red[0][t];
        #pragma unroll
        for (int q = 1; q < 8; ++q) {
            float4 r4 = red[q][t];
            s.x += r4.x; s.y += r4.y; s.z += r4.z; s.w += r4.w;
        }
        int col = jbase + t * 4;
        atomicAdd(accCur + col + 0, s.x);
        atomicAdd(accCur + col + 1, s.y);
        atomicAdd(accCur + col + 2, s.z);
        atomicAdd(accCur + col + 3, s.w);
    }
}

// ---------------------------------------------------------------------------
// Tail: out[col] = tanh(acc7[col] + bs[7][col]) — single float read per col.
// ---------------------------------------------------------------------------
__global__ __launch_bounds__(NTHREADS) void tail_kernel(
    const float* __restrict__ acc,
    const float* __restrict__ bs,
    float*       __restrict__ out)
{
    int i = blockIdx.x * NTHREADS + threadIdx.x;
    out[i] = tanhf(acc[i] + bs[(L_LAYERS - 1) * UNITS + i]);
}

// ---------------------------------------------------------------------------
extern "C" void kernel_launch(void* const* d_in, const int* in_sizes, int n_in,
                              void* d_out, int out_size, void* d_ws, size_t ws_size,
                              hipStream_t stream) {
    const float* x         = (const float*)d_in[0];
    const int*   node_inds = (const int*)  d_in[1];
    const float* Ws        = (const float*)d_in[2];
    const float* bs        = (const float*)d_in[3];
    float*       out       = (float*)d_out;
    float*       ws        = (float*)d_ws;

    float* outputs = ws;                 // TOTAL floats
    float* A0      = ws + TOTAL;         // 3 x UNITS accumulator rotation
    float* A1      = A0 + UNITS;
    float* A2      = A1 + UNITS;
    float* bufs[3] = { A0, A1, A2 };

    // Seed buf0 = 0 inside the capture (8 KB memset node; A1/A2 are zeroed
    // in-kernel by layers 0 and 1 before first use).
    hipMemsetAsync(A0, 0, UNITS * sizeof(float), stream);

    for (int i = 0; i < L_LAYERS; ++i) {
        layer_kernel<<<P_BLOCKS, NTHREADS, 0, stream>>>(
            i, x, node_inds, Ws, bs, outputs,
            bufs[(i + 2) % 3],   // accPrev  (== (i-1)%3; unused when i==0)
            bufs[i % 3],         // accCur
            bufs[(i + 1) % 3]);  // accNext (zeroed for layer i+1)
    }
    tail_kernel<<<UNITS / NTHREADS, NTHREADS, 0, stream>>>(
        bufs[(L_LAYERS - 1) % 3], bs, out);
}

// Round 9
// 405.114 us; speedup vs baseline: 1.0596x; 1.0596x over previous
//
#include <hip/hip_runtime.h>
#include <cmath>

// Problem constants (from reference)
#define N_INPUTS 2048
#define UNITS    2048
#define L_LAYERS 8
#define FANIN    4096
#define TOTAL    18432           // N_INPUTS + L*UNITS

// Decomposition: 8 k-chunks x 128 col-groups = 1024 blocks (4/CU).
// Block = 512 rows x 16 cols of W.
#define NTHREADS 256
#define KSPLIT   8                      // k-chunks
#define RKB      (FANIN / KSPLIT)       // 512 rows per block
#define JT       16                     // cols per block (one cacheline)
#define JG       (UNITS / JT)           // 128 col-groups
#define P_BLOCKS (KSPLIT * JG)          // 1024
#define PSTRIDE  (KSPLIT * JT)          // 128 floats per col-group region

// Partials layout: P[jg*PSTRIDE + kc*JT + c], c in [0,16).
//  - write side: block (kc,jg) stores 16 floats = ONE full 64B line.
//  - read side: activation col needs 8 floats in a 512B window -> 8 scalar
//    loads per thread, fully thread-parallel (no wave reduce, no atomics).

// ---------------------------------------------------------------------------
__global__ __launch_bounds__(NTHREADS, 4) void layer_kernel(
    int layer,
    const float* __restrict__ x,
    const int*   __restrict__ node_inds,
    const float* __restrict__ Ws,
    const float* __restrict__ bs,
    float*       __restrict__ outputs,
    const float* __restrict__ Pprev,
    float*       __restrict__ Pcur)
{
    const int b  = blockIdx.x;
    const int t  = threadIdx.x;
    const int jg = b & (JG - 1);     // 0..127 col-group
    const int kc = b >> 7;           // 0..7   k-chunk
    const int j0 = jg * JT;
    const int k0 = kc * RKB;
    const int c4 = t & 3;            // float4 slot within the 16 cols
    const int rr = t >> 2;           // 0..63  row phase

    __shared__ float  gsh[RKB];      // gathered activations (2 KB)
    __shared__ float4 redsh[4][4];   // per-wave column partials

    // ---- W tile first: 8 x float4 per thread. One wave instruction covers
    //      16 rows x 64B = 16 full cachelines (1 KB/instr). 8 independent
    //      loads in flight per thread -> 128 KB/CU outstanding: BW-saturating.
    const float* Wb = Ws + ((size_t)layer * FANIN + k0) * UNITS + j0 + c4 * 4;
    float4 w[8];
    #pragma unroll
    for (int i = 0; i < 8; ++i)
        w[i] = *(const float4*)(Wb + (size_t)(rr + 64 * i) * UNITS);

    // ---- gather: 2 rows per thread, fully thread-parallel.
    //      current-slot activation = 8-load window sum + bias + tanh.
    #pragma unroll
    for (int h = 0; h < 2; ++h) {
        int r   = t + h * NTHREADS;
        int idx = node_inds[layer * FANIN + k0 + r];
        float v;
        if (layer == 0) {
            v = (idx < N_INPUTS) ? x[idx] : 0.f;
        } else if (idx < layer * UNITS) {
            v = outputs[idx];
        } else if (idx < (layer + 1) * UNITS) {
            int col = idx - layer * UNITS;
            const float* pp = Pprev + (col >> 4) * PSTRIDE + (col & 15);
            float s = 0.f;
            #pragma unroll
            for (int q = 0; q < KSPLIT; ++q) s += pp[q * JT];
            v = tanhf(s + bs[(layer - 1) * UNITS + col]);
        } else {
            v = 0.f;
        }
        gsh[r] = v;
    }

    // ---- finalize state slot `layer` (kc==0 block of each col-group owns
    //      its 16 cols; same formula as the recompute path).
    if (kc == 0 && t < JT) {
        int col = j0 + t;
        float y;
        if (layer == 0) {
            y = x[col];
        } else {
            const float* pp = Pprev + jg * PSTRIDE + t;
            float s = 0.f;
            #pragma unroll
            for (int q = 0; q < KSPLIT; ++q) s += pp[q * JT];
            y = tanhf(s + bs[(layer - 1) * UNITS + col]);
        }
        outputs[(size_t)layer * UNITS + col] = y;
    }

    __syncthreads();

    // ---- FMA: 8 rows x 4 cols per thread from prefetched registers.
    //      gsh reads: 16 distinct addrs/wave, 4-lane broadcast -> conflict-free.
    float4 a; a.x = 0.f; a.y = 0.f; a.z = 0.f; a.w = 0.f;
    #pragma unroll
    for (int i = 0; i < 8; ++i) {
        float g = gsh[rr + 64 * i];
        a.x += g * w[i].x; a.y += g * w[i].y;
        a.z += g * w[i].z; a.w += g * w[i].w;
    }

    // ---- reduce across the 16 lanes sharing c4 (lanes c4, c4+4, .., c4+60)
    #pragma unroll
    for (int off = 4; off <= 32; off <<= 1) {
        a.x += __shfl_xor(a.x, off, 64);
        a.y += __shfl_xor(a.y, off, 64);
        a.z += __shfl_xor(a.z, off, 64);
        a.w += __shfl_xor(a.w, off, 64);
    }
    const int wv   = t >> 6;
    const int lane = t & 63;
    if (lane < 4) redsh[wv][lane] = a;     // lane == c4 here
    __syncthreads();

    // ---- combine 4 waves, store ONE full 64B line of partials
    if (t < 4) {
        float4 s0 = redsh[0][t], s1 = redsh[1][t];
        float4 s2 = redsh[2][t], s3 = redsh[3][t];
        float4 s;
        s.x = (s0.x + s1.x) + (s2.x + s3.x);
        s.y = (s0.y + s1.y) + (s2.y + s3.y);
        s.z = (s0.z + s1.z) + (s2.z + s3.z);
        s.w = (s0.w + s1.w) + (s2.w + s3.w);
        *(float4*)(Pcur + jg * PSTRIDE + kc * JT + t * 4) = s;
    }
}

// ---------------------------------------------------------------------------
// Tail: out[col] = tanh(sum_q P7[jg][q][c] + bs[7][col]) — thread-parallel.
// ---------------------------------------------------------------------------
__global__ __launch_bounds__(NTHREADS) void tail_kernel(
    const float* __restrict__ P,
    const float* __restrict__ bs,
    float*       __restrict__ out)
{
    int col = blockIdx.x * NTHREADS + threadIdx.x;
    const float* pp = P + (col >> 4) * PSTRIDE + (col & 15);
    float s = 0.f;
    #pragma unroll
    for (int q = 0; q < KSPLIT; ++q) s += pp[q * JT];
    out[col] = tanhf(s + bs[(L_LAYERS - 1) * UNITS + col]);
}

// ---------------------------------------------------------------------------
extern "C" void kernel_launch(void* const* d_in, const int* in_sizes, int n_in,
                              void* d_out, int out_size, void* d_ws, size_t ws_size,
                              hipStream_t stream) {
    const float* x         = (const float*)d_in[0];
    const int*   node_inds = (const int*)  d_in[1];
    const float* Ws        = (const float*)d_in[2];
    const float* bs        = (const float*)d_in[3];
    float*       out       = (float*)d_out;
    float*       ws        = (float*)d_ws;

    float* outputs = ws;                       // TOTAL floats
    float* P0      = ws + TOTAL;               // 16384 floats (64 KB)
    float* P1      = P0 + (size_t)JG * PSTRIDE;
    float* pbuf[2] = { P0, P1 };

    // Every P buffer is fully written before it is read within each replay
    // (layer i writes pbuf[i&1], layer i+1 reads it) -> poison-immune,
    // no memset, no atomics.
    for (int i = 0; i < L_LAYERS; ++i) {
        layer_kernel<<<P_BLOCKS, NTHREADS, 0, stream>>>(
            i, x, node_inds, Ws, bs, outputs,
            pbuf[(i + 1) & 1],   // Pprev (unused when i==0)
            pbuf[i & 1]);        // Pcur
    }
    tail_kernel<<<UNITS / NTHREADS, NTHREADS, 0, stream>>>(
        pbuf[(L_LAYERS - 1) & 1], bs, out);
}